// Round 16
// baseline (353.787 us; speedup 1.0000x reference)
//
#include <hip/hip_runtime.h>

#define NN 50000
#define NE 800000
#define CH 128
#define EPSV 1e-5f
#define NPASS 2
#define PRANGE 25000
#define NBLK 49        // ceil(NN/1024) scan blocks
#define XSCALE 5.0f    // fixed |x| bound for int8 (x ~ N(0,1))

typedef unsigned short ushort_t;
typedef __attribute__((ext_vector_type(8))) short short8_t;
typedef __attribute__((ext_vector_type(8))) unsigned short u16x8;
typedef __attribute__((ext_vector_type(4))) float f32x4;
typedef __attribute__((ext_vector_type(4))) unsigned int u32x4;

#define AS1 __attribute__((address_space(1)))
#define AS3 __attribute__((address_space(3)))

__device__ inline float bf2f(ushort_t u) {
    union { unsigned int i; float f; } t; t.i = ((unsigned int)u) << 16; return t.f;
}
__device__ inline ushort_t f2bf(float f) {
    union { float f; unsigned int i; } t; t.f = f;
    unsigned int r = t.i + 0x7fff + ((t.i >> 16) & 1);   // round-to-nearest-even
    return (ushort_t)(r >> 16);
}

// ---------------- CSR build ----------------

__global__ void k_hist(const int* __restrict__ dst, int* __restrict__ deg) {
    int e = blockIdx.x * 256 + threadIdx.x;
    if (e < NE) atomicAdd(&deg[dst[e]], 1);
}

__global__ __launch_bounds__(1024) void k_scanA(const int* __restrict__ deg,
                                                int* __restrict__ rp,
                                                int* __restrict__ btot) {
    __shared__ int wsum[16];
    const int t = threadIdx.x;
    const int lane = t & 63;
    const int wid = t >> 6;
    const int i = blockIdx.x * 1024 + t;
    int v = (i < NN) ? deg[i] : 0;
    int x = v;
    #pragma unroll
    for (int off = 1; off < 64; off <<= 1) {
        int y = __shfl_up(x, off, 64);
        if (lane >= off) x += y;
    }
    if (lane == 63) wsum[wid] = x;
    __syncthreads();
    if (wid == 0 && lane < 16) {
        int s = wsum[lane];
        #pragma unroll
        for (int off = 1; off < 16; off <<= 1) {
            int y = __shfl_up(s, off, 16);
            if (lane >= off) s += y;
        }
        wsum[lane] = s;
    }
    __syncthreads();
    int wbase = (wid > 0) ? wsum[wid - 1] : 0;
    if (i < NN) rp[i] = wbase + x - v;
    if (wid == 15 && lane == 63) btot[blockIdx.x] = wbase + x;
}

__global__ void k_scanB(const int* __restrict__ btot, int* __restrict__ boffs,
                        int* __restrict__ rp) {
    int t = threadIdx.x;                  // 64 threads
    int v = (t < NBLK) ? btot[t] : 0;
    int x = v;
    #pragma unroll
    for (int off = 1; off < 64; off <<= 1) {
        int y = __shfl_up(x, off, 64);
        if (t >= off) x += y;
    }
    if (t < NBLK) boffs[t] = x - v;
    if (t == NBLK - 1) rp[NN] = x;        // = NE
}

__global__ __launch_bounds__(256) void k_scanC(int* __restrict__ rp,
                                               const int* __restrict__ boffs) {
    int i = blockIdx.x * 256 + threadIdx.x;
    if (i < NN) rp[i] += boffs[i >> 10];
}

__global__ void k_fillp(const int* __restrict__ src, const int* __restrict__ dst,
                        const int* __restrict__ rp, int* __restrict__ cur,
                        int* __restrict__ csr, int lo, int hi) {
    int e = blockIdx.x * 256 + threadIdx.x;
    if (e < NE) {
        int d = dst[e];
        int s = src[e];
        if (d >= lo && d < hi) {
            int pos = rp[d] + atomicAdd(&cur[d], 1);
            csr[pos] = s;
        }
    }
}

// ---------------- input convert (bf16 + int8, fixed scale) + layer-1 pack ---

__global__ __launch_bounds__(256) void k_cvtpack(const float* __restrict__ x,
        ushort_t* __restrict__ xb, signed char* __restrict__ xq,
        const float* __restrict__ s0, const float* __restrict__ s1,
        ushort_t* __restrict__ Wp1, float* __restrict__ bn_sums,
        float* __restrict__ sdx) {
    if (blockIdx.x < 6250) {
        int i = blockIdx.x * 256 + threadIdx.x;      // float4 index
        if (blockIdx.x == 0) {
            bn_sums[threadIdx.x] = 0.f;
            bn_sums[256 + threadIdx.x] = 0.f;
            bn_sums[512 + threadIdx.x] = 0.f;
        }
        if (i >= NN * 32) return;
        float4 v = ((const float4*)x)[i];
        ushort4 o;
        o.x = f2bf(v.x); o.y = f2bf(v.y); o.z = f2bf(v.z); o.w = f2bf(v.w);
        ((ushort4*)xb)[i] = o;
        const float inv = 127.0f / XSCALE;
        float vv[4] = {v.x, v.y, v.z, v.w};
        unsigned pk = 0;
        #pragma unroll
        for (int k = 0; k < 4; ++k) {
            int qv = __float2int_rn(vv[k] * inv);
            qv = qv > 127 ? 127 : (qv < -127 ? -127 : qv);
            pk |= ((unsigned)(qv & 0xFF)) << (8 * k);
        }
        ((unsigned*)xq)[i] = pk;
    } else if (blockIdx.x < 6250 + 128) {
        int t = (blockIdx.x - 6250) * 256 + threadIdx.x;   // 128*256
        int o = t >> 8, k = t & 255;
        float v = (k < 128) ? s0[o * 128 + k] : s1[o * 128 + k - 128];
        Wp1[t] = f2bf(v);
    } else {
        if (threadIdx.x < 128) sdx[threadIdx.x] = XSCALE / 127.0f;
    }
}

// ---------------- fused BN-finalize + next-layer fold + requantize ----------
// 256 threads. blocks [0,128): fold (GUARDED to k<128 — r15 bug was threads
// 128..255 running the 128-thread fold body, clobbering Wp/abg/sdec/red).
// blocks [128,...): requant y (bf16) -> int8 qout, scale recomputed inline.

__global__ void k_foldreq(const float* __restrict__ bn_sums,
                          const float* __restrict__ g, const float* __restrict__ b,
                          const float* __restrict__ Wl, const float* __restrict__ Wr,
                          const float* __restrict__ bl,
                          ushort_t* __restrict__ Wp, float* __restrict__ bias,
                          float* __restrict__ abg, float* __restrict__ sdec,
                          const ushort_t* __restrict__ y,
                          signed char* __restrict__ qout) {
    if (blockIdx.x < 128) {
        __shared__ float red[128];
        int o = blockIdx.x;
        int k = threadIdx.x;
        if (k < 128) {
            float mu = bn_sums[k] * (1.0f / NN);
            float var = bn_sums[128 + k] * (1.0f / NN) - mu * mu;
            var = var > 0.f ? var : 0.f;
            float a = g[k] * rsqrtf(var + EPSV);
            float c = b[k] - a * mu;
            if (o == 0) {
                abg[k] = a; abg[128 + k] = c;
                sdec[k] = (mu + 8.0f * sqrtf(var)) * (1.0f / 127.0f);
            }
            float wr = Wr[o * 128 + k];
            Wp[o * 256 + k]       = f2bf(Wl[o * 128 + k]);
            Wp[o * 256 + 128 + k] = f2bf(wr * a);
            red[k] = wr * c;
        }
        __syncthreads();
        for (int s = 64; s > 0; s >>= 1) {
            if (k < s) red[k] += red[k + s];
            __syncthreads();
        }
        if (k == 0) bias[o] = bl[o] + red[0];
    } else {
        int i = (blockIdx.x - 128) * 256 + threadIdx.x;  // u16x8 index
        if (i >= NN * 16) return;
        u16x8 v = *(const u16x8*)&y[(size_t)i * 8];
        int c0 = (i * 8) & 127;
        unsigned lo = 0, hi = 0;
        #pragma unroll
        for (int k = 0; k < 8; ++k) {
            float mu = bn_sums[c0 + k] * (1.0f / NN);
            float var = bn_sums[128 + c0 + k] * (1.0f / NN) - mu * mu;
            var = var > 0.f ? var : 0.f;
            float vm = mu + 8.0f * sqrtf(var);
            float sinv = vm > 1e-10f ? 127.0f / vm : 0.f;
            int qv = __float2int_rn(bf2f(v[k]) * sinv);  // y >= 0
            qv = qv > 127 ? 127 : qv;
            if (k < 4) lo |= ((unsigned)(qv & 0xFF)) << (8 * k);
            else       hi |= ((unsigned)(qv & 0xFF)) << (8 * (k - 4));
        }
        ((uint2*)qout)[i] = make_uint2(lo, hi);
    }
}

// final fold: layer-3 BN finalize + Wlin fold (uses stored ab1, ab2)
__global__ void k_foldF(const float* __restrict__ bn3,
                        const float* __restrict__ g3, const float* __restrict__ b3,
                        const float* __restrict__ ab1, const float* __restrict__ ab2,
                        const float* __restrict__ Wlin, const float* __restrict__ blin,
                        ushort_t* __restrict__ Wp, float* __restrict__ bias) {
    __shared__ float red[128];
    int o = blockIdx.x;
    int k = threadIdx.x;                  // 128 threads
    float mu = bn3[k] * (1.0f / NN);
    float var = bn3[128 + k] * (1.0f / NN) - mu * mu;
    var = var > 0.f ? var : 0.f;
    float a3 = g3[k] * rsqrtf(var + EPSV);
    float c3 = b3[k] - a3 * mu;
    float w1 = Wlin[o * 384 + k];
    float w2 = Wlin[o * 384 + 128 + k];
    float w3 = Wlin[o * 384 + 256 + k];
    Wp[o * 384 + k]       = f2bf(w1 * ab1[k]);
    Wp[o * 384 + 128 + k] = f2bf(w2 * ab2[k]);
    Wp[o * 384 + 256 + k] = f2bf(w3 * a3);
    red[k] = w1 * ab1[128 + k] + w2 * ab2[128 + k] + w3 * c3;
    __syncthreads();
    for (int s = 64; s > 0; s >>= 1) {
        if (k < s) red[k] += red[k + s];
        __syncthreads();
    }
    if (k == 0) bias[o] = blin[o] + red[0];
}

// ---------------- mean aggregation: int8, 8 lanes/row, 16B/lane -------------
// One wave per node. 8 octets x 8 lanes; each lane loads 16B (16 int8 ch) of
// its octet's edge row -> one wave VMEM instr gathers 8 edges (2x fewer
// instrs than the 16-lane/row variant; gather shown byte-invariant in r14).
// 2 streams/octet = 16 edges in flight per iter. Integer accumulate, scale
// folds out of loop. FOLD: out = deg>0 ? a*mean + c : 0.

#define ACCW(acc, w, base) do {                                            \
    unsigned w_ = (w);                                                     \
    acc[(base) + 0] += (int)(signed char)(w_ & 0xFF);                      \
    acc[(base) + 1] += (int)(signed char)((w_ >> 8) & 0xFF);               \
    acc[(base) + 2] += (int)(signed char)((w_ >> 16) & 0xFF);              \
    acc[(base) + 3] += (int)(signed char)(w_ >> 24);                       \
} while (0)

#define ACCI16(acc, w) do {                                                \
    ACCW(acc, (w)[0], 0); ACCW(acc, (w)[1], 4);                            \
    ACCW(acc, (w)[2], 8); ACCW(acc, (w)[3], 12);                           \
} while (0)

template<bool FOLD>
__global__ __launch_bounds__(256) void k_aggr8(const signed char* __restrict__ xq,
        const int* __restrict__ rp, const int* __restrict__ csr,
        const float* __restrict__ sd, const float* __restrict__ ab,
        ushort_t* __restrict__ aggr) {
    const int node = blockIdx.x * 4 + (threadIdx.x >> 6);   // grid = NN/4 exact
    const int lane = threadIdx.x & 63;
    const int l8  = lane & 7;        // channel group: ch l8*16 .. l8*16+15
    const int oct = lane >> 3;       // edge phase 0..7
    const int r0 = rp[node], r1 = rp[node + 1];
    const int d = r1 - r0;
    const signed char* xrow = xq + l8 * 16;

    int accA[16], accB[16];
    #pragma unroll
    for (int i = 0; i < 16; ++i) { accA[i] = 0; accB[i] = 0; }

    int j = r0 + oct;
    for (; j + 8 < r1; j += 16) {    // 16 edges per wave-iter (2 per octet)
        int s0 = csr[j], s1 = csr[j + 8];
        u32x4 w0 = *(const u32x4*)(xrow + (size_t)s0 * CH);
        u32x4 w1 = *(const u32x4*)(xrow + (size_t)s1 * CH);
        ACCI16(accA, w0);
        ACCI16(accB, w1);
    }
    if (j < r1) {
        u32x4 w0 = *(const u32x4*)(xrow + (size_t)csr[j] * CH);
        ACCI16(accA, w0);
    }

    const float scdeg = d > 0 ? 1.0f / (float)d : 0.0f;
    float af[16];
    #pragma unroll
    for (int i = 0; i < 16; ++i) {
        int s = accA[i] + accB[i];
        s += __shfl_xor(s, 8);
        s += __shfl_xor(s, 16);
        s += __shfl_xor(s, 32);
        af[i] = (float)s * scdeg;
    }

    if (oct == 0) {                  // lanes 0..7 write 32B each (contiguous)
        u16x8 ov0, ov1;
        #pragma unroll
        for (int i = 0; i < 16; ++i) {
            int c = l8 * 16 + i;
            float v = af[i] * sd[c];
            if (FOLD) v = d > 0 ? fmaf(v, ab[c], ab[128 + c]) : 0.f;
            if (i < 8) ov0[i] = f2bf(v);
            else       ov1[i - 8] = f2bf(v);
        }
        *(u16x8*)&aggr[(size_t)node * CH + l8 * 16] = ov0;
        *(u16x8*)&aggr[(size_t)node * CH + l8 * 16 + 8] = ov1;
    }
}

// ---------------- MFMA GEMM: out = relu([A0|A1|A2] @ Wpack.T + bias) --------
// Round-9 proven. A concat along K (NT tiles of 64). Wpack: [128][NT*64] bf16.
// 128x128 block, 4 waves at 64x64, XOR-swizzled LDS via pre-swizzled source.

#define STAGE(buf, t) do {                                                           \
    const ushort_t* Ab_ = (((t) >> 1) == 0) ? A0 : ((((t) >> 1) == 1) ? A1 : A2);    \
    Ab_ += ((t) & 1) * 64;                                                           \
    const ushort_t* Wb_ = W + (t) * 64;                                              \
    _Pragma("unroll")                                                                \
    for (int i_ = 0; i_ < 4; ++i_) {                                                 \
        int f_ = i_ * 256 + tid;                                                     \
        int row_ = f_ >> 3;                                                          \
        int c_ = (f_ & 7) ^ (row_ & 7);                                              \
        int gr_ = bn0 + row_; gr_ = gr_ < NN ? gr_ : NN - 1;                         \
        __builtin_amdgcn_global_load_lds(                                            \
            (const AS1 unsigned int*)(Ab_ + (size_t)gr_ * CH + c_ * 8),              \
            (AS3 unsigned int*)(&Abuf[buf][f_ * 8]), 16, 0, 0);                      \
        __builtin_amdgcn_global_load_lds(                                            \
            (const AS1 unsigned int*)(Wb_ + (size_t)row_ * (NT * 64) + c_ * 8),      \
            (AS3 unsigned int*)(&Wbuf[buf][f_ * 8]), 16, 0, 0);                      \
    } } while (0)

template<int NT, bool STATS, bool F32OUT>
__global__ __launch_bounds__(256, 2) void k_mgemm(
    const ushort_t* __restrict__ A0, const ushort_t* __restrict__ A1,
    const ushort_t* __restrict__ A2,
    const ushort_t* __restrict__ W, const float* __restrict__ bias,
    ushort_t* __restrict__ outb, float* __restrict__ outf,
    float* __restrict__ bn_sums)
{
    __shared__ __align__(16) ushort_t Abuf[2][128 * 64];
    __shared__ __align__(16) ushort_t Wbuf[2][128 * 64];
    __shared__ float bns[128], bnq[128];

    const int tid  = threadIdx.x;
    const int lane = tid & 63;
    const int wid  = tid >> 6;
    const int l15  = lane & 15;
    const int lg   = lane >> 4;
    const int wn   = (wid >> 1) * 64;
    const int wo   = (wid & 1) * 64;
    const int bn0  = blockIdx.x * 128;

    if (STATS && tid < 128) { bns[tid] = 0.f; bnq[tid] = 0.f; }

    f32x4 acc[4][4];
    #pragma unroll
    for (int i = 0; i < 4; ++i)
        #pragma unroll
        for (int j = 0; j < 4; ++j)
            acc[i][j] = (f32x4){0.f, 0.f, 0.f, 0.f};

    STAGE(0, 0);
    asm volatile("s_waitcnt vmcnt(0)");
    __syncthreads();

    #pragma unroll
    for (int t = 0; t < NT; ++t) {
        const int cur = t & 1;
        if (t + 1 < NT) STAGE(cur ^ 1, t + 1);
        #pragma unroll
        for (int s = 0; s < 2; ++s) {
            short8_t af[4], wf[4];
            #pragma unroll
            for (int b = 0; b < 4; ++b) {
                int ra = wn + b * 16 + l15;
                int ca = (s * 4 + lg) ^ (ra & 7);
                af[b] = *(const short8_t*)&Abuf[cur][ra * 64 + ca * 8];
                int rw = wo + b * 16 + l15;
                int cw = (s * 4 + lg) ^ (rw & 7);
                wf[b] = *(const short8_t*)&Wbuf[cur][rw * 64 + cw * 8];
            }
            #pragma unroll
            for (int i = 0; i < 4; ++i)
                #pragma unroll
                for (int j = 0; j < 4; ++j)
                    acc[i][j] = __builtin_amdgcn_mfma_f32_16x16x32_bf16(
                        af[i], wf[j], acc[i][j], 0, 0, 0);
        }
        asm volatile("s_waitcnt vmcnt(0)");
        __syncthreads();
    }

    float bv[4];
    #pragma unroll
    for (int j = 0; j < 4; ++j) bv[j] = bias[wo + j * 16 + l15];

    float sum[4] = {0.f, 0.f, 0.f, 0.f}, sq[4] = {0.f, 0.f, 0.f, 0.f};

    #pragma unroll
    for (int i = 0; i < 4; ++i) {
        #pragma unroll
        for (int r = 0; r < 4; ++r) {
            int gn = bn0 + wn + i * 16 + lg * 4 + r;
            bool ok = gn < NN;
            #pragma unroll
            for (int j = 0; j < 4; ++j) {
                int o = wo + j * 16 + l15;
                float v = acc[i][j][r] + bv[j];
                v = fmaxf(v, 0.f);
                if (ok) {
                    if (F32OUT) outf[(size_t)gn * CH + o] = v;
                    else        outb[(size_t)gn * CH + o] = f2bf(v);
                    if (STATS) { sum[j] += v; sq[j] += v * v; }
                }
            }
        }
    }

    if (STATS) {
        #pragma unroll
        for (int j = 0; j < 4; ++j) {
            float ss = sum[j], qq = sq[j];
            ss += __shfl_xor(ss, 16); qq += __shfl_xor(qq, 16);
            ss += __shfl_xor(ss, 32); qq += __shfl_xor(qq, 32);
            if (lg == 0) {
                atomicAdd(&bns[wo + j * 16 + l15], ss);
                atomicAdd(&bnq[wo + j * 16 + l15], qq);
            }
        }
        __syncthreads();
        if (tid < 128) {
            atomicAdd(&bn_sums[tid], bns[tid]);
            atomicAdd(&bn_sums[128 + tid], bnq[tid]);
        }
    }
}

// ---------------- driver ----------------

extern "C" void kernel_launch(void* const* d_in, const int* in_sizes, int n_in,
                              void* d_out, int out_size, void* d_ws, size_t ws_size,
                              hipStream_t stream) {
    const float* x  = (const float*)d_in[0];
    const int*   ei = (const int*)d_in[1];
    const int* esrc = ei;
    const int* edst = ei + NE;

    const float* Wl[3] = {(const float*)d_in[2],  (const float*)d_in[7],  (const float*)d_in[12]};
    const float* bl[3] = {(const float*)d_in[3],  (const float*)d_in[8],  (const float*)d_in[13]};
    const float* Wr[3] = {(const float*)d_in[4],  (const float*)d_in[9],  (const float*)d_in[14]};
    const float* gg[3] = {(const float*)d_in[5],  (const float*)d_in[10], (const float*)d_in[15]};
    const float* bb[3] = {(const float*)d_in[6],  (const float*)d_in[11], (const float*)d_in[16]};
    const float* Wlin  = (const float*)d_in[17];
    const float* blin  = (const float*)d_in[18];

    float* fo = (float*)d_out;

    const size_t NC = (size_t)NN * CH;
    ushort_t* xb       = (ushort_t*)d_ws;
    ushort_t* y1b      = xb + NC;
    ushort_t* y2b      = y1b + NC;
    ushort_t* aggr_b   = y2b + NC;
    signed char* xq    = (signed char*)(aggr_b + NC);  // NC bytes, dead after aggr1
    signed char* y1q   = xq + NC;                      // NC bytes, dead after aggr2
    ushort_t* y3b      = (ushort_t*)xq;                // aliases xq+y1q (2*NC bytes)
    signed char* y2q   = y1q + NC;                     // NC bytes
    ushort_t* Wp1      = (ushort_t*)(y2q + NC);        // [128][256]
    ushort_t* Wp2      = Wp1 + 128 * 256;
    ushort_t* Wp3      = Wp2 + 128 * 256;
    ushort_t* WpF      = Wp3 + 128 * 256;              // [128][384]
    float* bias2       = (float*)(WpF + 128 * 384);
    float* bias3       = bias2 + 128;
    float* biasF       = bias3 + 128;
    float* bn_sums     = biasF + 128;                  // 3 x 256
    float* ab          = bn_sums + 768;                // 2 x 256 {a,c}
    float* sdx         = ab + 512;                     // 128 decode scales (x)
    float* sd1         = sdx + 128;
    float* sd2         = sd1 + 128;
    int* btot          = (int*)(sd2 + 128);            // 64
    int* boffs         = btot + 64;                    // 64
    int* deg           = boffs + 64;                   // NN
    int* cur           = deg + NN;                     // NN
    int* rp            = cur + NN;                     // NN+1
    int* csr           = rp + NN + 1;                  // NE

    // ---- CSR build ----
    hipMemsetAsync(deg, 0, 2 * NN * sizeof(int), stream);   // deg + cur
    k_hist<<<(NE + 255) / 256, 256, 0, stream>>>(edst, deg);
    k_scanA<<<NBLK, 1024, 0, stream>>>(deg, rp, btot);
    k_scanB<<<1, 64, 0, stream>>>(btot, boffs, rp);
    k_scanC<<<(NN + 255) / 256, 256, 0, stream>>>(rp, boffs);
    for (int p = 0; p < NPASS; ++p)
        k_fillp<<<NE / 256, 256, 0, stream>>>(esrc, edst, rp, cur, csr,
                                              p * PRANGE, (p + 1) * PRANGE);

    // ---- convert (bf16 + int8 fixed-scale) + layer-1 pack + bn_sums zero ----
    k_cvtpack<<<6250 + 128 + 1, 256, 0, stream>>>(x, xb, xq,
                                                  Wl[0], Wr[0], Wp1, bn_sums, sdx);

    const int GEMM_GRID = (NN + 127) / 128;        // 391
    const int AGGR_GRID = NN / 4;                  // 12500 (wave per node)
    const int FOLD_GRID = 128 + (NN * 16 + 255) / 256;

    // ---- layer 1 ----
    k_aggr8<false><<<AGGR_GRID, 256, 0, stream>>>(xq, rp, csr, sdx, nullptr, aggr_b);
    k_mgemm<4, true, false><<<GEMM_GRID, 256, 0, stream>>>(
        aggr_b, xb, nullptr, Wp1, bl[0], y1b, nullptr, bn_sums);
    k_foldreq<<<FOLD_GRID, 256, 0, stream>>>(bn_sums, gg[0], bb[0],
        Wl[1], Wr[1], bl[1], Wp2, bias2, ab, sd1, y1b, y1q);

    // ---- layer 2 ----
    k_aggr8<true><<<AGGR_GRID, 256, 0, stream>>>(y1q, rp, csr, sd1, ab, aggr_b);
    k_mgemm<4, true, false><<<GEMM_GRID, 256, 0, stream>>>(
        aggr_b, y1b, nullptr, Wp2, bias2, y2b, nullptr, bn_sums + 256);
    k_foldreq<<<FOLD_GRID, 256, 0, stream>>>(bn_sums + 256, gg[1], bb[1],
        Wl[2], Wr[2], bl[2], Wp3, bias3, ab + 256, sd2, y2b, y2q);

    // ---- layer 3 (y3b aliases dead xq+y1q region) ----
    k_aggr8<true><<<AGGR_GRID, 256, 0, stream>>>(y2q, rp, csr, sd2, ab + 256, aggr_b);
    k_mgemm<4, true, false><<<GEMM_GRID, 256, 0, stream>>>(
        aggr_b, y2b, nullptr, Wp3, bias3, y3b, nullptr, bn_sums + 512);
    k_foldF<<<128, 128, 0, stream>>>(bn_sums + 512, gg[2], bb[2], ab, ab + 256,
                                     Wlin, blin, WpF, biasF);

    // ---- final: relu([y1|y2|y3] @ WpF.T + biasF) -> fp32 d_out ----
    k_mgemm<6, false, true><<<GEMM_GRID, 256, 0, stream>>>(
        y1b, y2b, y3b, WpF, biasF, nullptr, fo, nullptr);
}

// Round 17
// 323.969 us; speedup vs baseline: 1.0920x; 1.0920x over previous
//
#include <hip/hip_runtime.h>

#define NN 50000
#define NE 800000
#define CH 128
#define EPSV 1e-5f
#define NPASS 2
#define PRANGE 25000
#define NBLK 49        // ceil(NN/1024) scan blocks
#define XSCALE 5.0f    // fixed |x| bound for int8 (x ~ N(0,1))

typedef unsigned short ushort_t;
typedef __attribute__((ext_vector_type(8))) short short8_t;
typedef __attribute__((ext_vector_type(8))) unsigned short u16x8;
typedef __attribute__((ext_vector_type(4))) float f32x4;

#define AS1 __attribute__((address_space(1)))
#define AS3 __attribute__((address_space(3)))

__device__ inline float bf2f(ushort_t u) {
    union { unsigned int i; float f; } t; t.i = ((unsigned int)u) << 16; return t.f;
}
__device__ inline ushort_t f2bf(float f) {
    union { float f; unsigned int i; } t; t.f = f;
    unsigned int r = t.i + 0x7fff + ((t.i >> 16) & 1);   // round-to-nearest-even
    return (ushort_t)(r >> 16);
}

// ---------------- CSR build ----------------

__global__ void k_hist(const int* __restrict__ dst, int* __restrict__ deg) {
    int e = blockIdx.x * 256 + threadIdx.x;
    if (e < NE) atomicAdd(&deg[dst[e]], 1);
}

__global__ __launch_bounds__(1024) void k_scanA(const int* __restrict__ deg,
                                                int* __restrict__ rp,
                                                int* __restrict__ btot) {
    __shared__ int wsum[16];
    const int t = threadIdx.x;
    const int lane = t & 63;
    const int wid = t >> 6;
    const int i = blockIdx.x * 1024 + t;
    int v = (i < NN) ? deg[i] : 0;
    int x = v;
    #pragma unroll
    for (int off = 1; off < 64; off <<= 1) {
        int y = __shfl_up(x, off, 64);
        if (lane >= off) x += y;
    }
    if (lane == 63) wsum[wid] = x;
    __syncthreads();
    if (wid == 0 && lane < 16) {
        int s = wsum[lane];
        #pragma unroll
        for (int off = 1; off < 16; off <<= 1) {
            int y = __shfl_up(s, off, 16);
            if (lane >= off) s += y;
        }
        wsum[lane] = s;
    }
    __syncthreads();
    int wbase = (wid > 0) ? wsum[wid - 1] : 0;
    if (i < NN) rp[i] = wbase + x - v;
    if (wid == 15 && lane == 63) btot[blockIdx.x] = wbase + x;
}

__global__ void k_scanB(const int* __restrict__ btot, int* __restrict__ boffs,
                        int* __restrict__ rp) {
    int t = threadIdx.x;                  // 64 threads
    int v = (t < NBLK) ? btot[t] : 0;
    int x = v;
    #pragma unroll
    for (int off = 1; off < 64; off <<= 1) {
        int y = __shfl_up(x, off, 64);
        if (t >= off) x += y;
    }
    if (t < NBLK) boffs[t] = x - v;
    if (t == NBLK - 1) rp[NN] = x;        // = NE
}

__global__ __launch_bounds__(256) void k_scanC(int* __restrict__ rp,
                                               const int* __restrict__ boffs) {
    int i = blockIdx.x * 256 + threadIdx.x;
    if (i < NN) rp[i] += boffs[i >> 10];
}

__global__ void k_fillp(const int* __restrict__ src, const int* __restrict__ dst,
                        const int* __restrict__ rp, int* __restrict__ cur,
                        int* __restrict__ csr, int lo, int hi) {
    int e = blockIdx.x * 256 + threadIdx.x;
    if (e < NE) {
        int d = dst[e];
        int s = src[e];
        if (d >= lo && d < hi) {
            int pos = rp[d] + atomicAdd(&cur[d], 1);
            csr[pos] = s;
        }
    }
}

// ---------------- input convert (bf16 + int8, fixed scale) + layer-1 pack ---

__global__ __launch_bounds__(256) void k_cvtpack(const float* __restrict__ x,
        ushort_t* __restrict__ xb, signed char* __restrict__ xq,
        const float* __restrict__ s0, const float* __restrict__ s1,
        ushort_t* __restrict__ Wp1, float* __restrict__ bn_sums,
        float* __restrict__ sdx) {
    if (blockIdx.x < 6250) {
        int i = blockIdx.x * 256 + threadIdx.x;      // float4 index
        if (blockIdx.x == 0) {
            bn_sums[threadIdx.x] = 0.f;
            bn_sums[256 + threadIdx.x] = 0.f;
            bn_sums[512 + threadIdx.x] = 0.f;
        }
        if (i >= NN * 32) return;
        float4 v = ((const float4*)x)[i];
        ushort4 o;
        o.x = f2bf(v.x); o.y = f2bf(v.y); o.z = f2bf(v.z); o.w = f2bf(v.w);
        ((ushort4*)xb)[i] = o;
        const float inv = 127.0f / XSCALE;
        float vv[4] = {v.x, v.y, v.z, v.w};
        unsigned pk = 0;
        #pragma unroll
        for (int k = 0; k < 4; ++k) {
            int qv = __float2int_rn(vv[k] * inv);
            qv = qv > 127 ? 127 : (qv < -127 ? -127 : qv);
            pk |= ((unsigned)(qv & 0xFF)) << (8 * k);
        }
        ((unsigned*)xq)[i] = pk;
    } else if (blockIdx.x < 6250 + 128) {
        int t = (blockIdx.x - 6250) * 256 + threadIdx.x;   // 128*256
        int o = t >> 8, k = t & 255;
        float v = (k < 128) ? s0[o * 128 + k] : s1[o * 128 + k - 128];
        Wp1[t] = f2bf(v);
    } else {
        if (threadIdx.x < 128) sdx[threadIdx.x] = XSCALE / 127.0f;
    }
}

// ---------------- fused BN-finalize + next-layer fold + requantize ----------
// 256 threads. blocks [0,128): fold (guarded to k<128 — r15 lesson).
// blocks [128,...): requant y (bf16) -> int8 qout, scale recomputed inline.

__global__ void k_foldreq(const float* __restrict__ bn_sums,
                          const float* __restrict__ g, const float* __restrict__ b,
                          const float* __restrict__ Wl, const float* __restrict__ Wr,
                          const float* __restrict__ bl,
                          ushort_t* __restrict__ Wp, float* __restrict__ bias,
                          float* __restrict__ abg, float* __restrict__ sdec,
                          const ushort_t* __restrict__ y,
                          signed char* __restrict__ qout) {
    if (blockIdx.x < 128) {
        __shared__ float red[128];
        int o = blockIdx.x;
        int k = threadIdx.x;
        if (k < 128) {
            float mu = bn_sums[k] * (1.0f / NN);
            float var = bn_sums[128 + k] * (1.0f / NN) - mu * mu;
            var = var > 0.f ? var : 0.f;
            float a = g[k] * rsqrtf(var + EPSV);
            float c = b[k] - a * mu;
            if (o == 0) {
                abg[k] = a; abg[128 + k] = c;
                sdec[k] = (mu + 8.0f * sqrtf(var)) * (1.0f / 127.0f);
            }
            float wr = Wr[o * 128 + k];
            Wp[o * 256 + k]       = f2bf(Wl[o * 128 + k]);
            Wp[o * 256 + 128 + k] = f2bf(wr * a);
            red[k] = wr * c;
        }
        __syncthreads();
        for (int s = 64; s > 0; s >>= 1) {
            if (k < s) red[k] += red[k + s];
            __syncthreads();
        }
        if (k == 0) bias[o] = bl[o] + red[0];
    } else {
        int i = (blockIdx.x - 128) * 256 + threadIdx.x;  // u16x8 index
        if (i >= NN * 16) return;
        u16x8 v = *(const u16x8*)&y[(size_t)i * 8];
        int c0 = (i * 8) & 127;
        unsigned lo = 0, hi = 0;
        #pragma unroll
        for (int k = 0; k < 8; ++k) {
            float mu = bn_sums[c0 + k] * (1.0f / NN);
            float var = bn_sums[128 + c0 + k] * (1.0f / NN) - mu * mu;
            var = var > 0.f ? var : 0.f;
            float vm = mu + 8.0f * sqrtf(var);
            float sinv = vm > 1e-10f ? 127.0f / vm : 0.f;
            int qv = __float2int_rn(bf2f(v[k]) * sinv);  // y >= 0
            qv = qv > 127 ? 127 : qv;
            if (k < 4) lo |= ((unsigned)(qv & 0xFF)) << (8 * k);
            else       hi |= ((unsigned)(qv & 0xFF)) << (8 * (k - 4));
        }
        ((uint2*)qout)[i] = make_uint2(lo, hi);
    }
}

// final fold: layer-3 BN finalize + Wlin fold (uses stored ab1, ab2)
__global__ void k_foldF(const float* __restrict__ bn3,
                        const float* __restrict__ g3, const float* __restrict__ b3,
                        const float* __restrict__ ab1, const float* __restrict__ ab2,
                        const float* __restrict__ Wlin, const float* __restrict__ blin,
                        ushort_t* __restrict__ Wp, float* __restrict__ bias) {
    __shared__ float red[128];
    int o = blockIdx.x;
    int k = threadIdx.x;                  // 128 threads
    float mu = bn3[k] * (1.0f / NN);
    float var = bn3[128 + k] * (1.0f / NN) - mu * mu;
    var = var > 0.f ? var : 0.f;
    float a3 = g3[k] * rsqrtf(var + EPSV);
    float c3 = b3[k] - a3 * mu;
    float w1 = Wlin[o * 384 + k];
    float w2 = Wlin[o * 384 + 128 + k];
    float w3 = Wlin[o * 384 + 256 + k];
    Wp[o * 384 + k]       = f2bf(w1 * ab1[k]);
    Wp[o * 384 + 128 + k] = f2bf(w2 * ab2[k]);
    Wp[o * 384 + 256 + k] = f2bf(w3 * a3);
    red[k] = w1 * ab1[128 + k] + w2 * ab2[128 + k] + w3 * c3;
    __syncthreads();
    for (int s = 64; s > 0; s >>= 1) {
        if (k < s) red[k] += red[k + s];
        __syncthreads();
    }
    if (k == 0) bias[o] = blin[o] + red[0];
}

// ---------------- mean aggregation: int8, 16 lanes/row, 4 streams -----------
// r14-proven shape (48.1us): one wave per node; 16 lanes cover the 128B int8
// row (8B/lane); 4 quarters x 4 streams = 16 edge-rows in flight per iter —
// the max concurrency at mean degree 16, which r14/r16 showed is the binding
// constraint (time tracks streams, not bytes, not instruction count).
// Integer accumulate; scale folds out of loop. FOLD: out = deg>0 ? a*mean+c : 0.

#define ACCI(acc, w) do {                                                  \
    unsigned a0_ = (w).x, a1_ = (w).y;                                     \
    acc[0] += (int)(signed char)(a0_);                                     \
    acc[1] += (int)(signed char)(a0_ >> 8);                                \
    acc[2] += (int)(signed char)(a0_ >> 16);                               \
    acc[3] += (int)(signed char)(a0_ >> 24);                               \
    acc[4] += (int)(signed char)(a1_);                                     \
    acc[5] += (int)(signed char)(a1_ >> 8);                                \
    acc[6] += (int)(signed char)(a1_ >> 16);                               \
    acc[7] += (int)(signed char)(a1_ >> 24);                               \
} while (0)

template<bool FOLD>
__global__ __launch_bounds__(256) void k_aggr8(const signed char* __restrict__ xq,
        const int* __restrict__ rp, const int* __restrict__ csr,
        const float* __restrict__ sd, const float* __restrict__ ab,
        ushort_t* __restrict__ aggr) {
    const int node = blockIdx.x * 4 + (threadIdx.x >> 6);   // grid = NN/4 exact
    const int lane = threadIdx.x & 63;
    const int l4 = lane & 15;        // channel group: ch l4*8 .. l4*8+7
    const int q  = lane >> 4;        // edge phase 0..3
    const int r0 = rp[node], r1 = rp[node + 1];
    const int d = r1 - r0;
    const signed char* xrow = xq + l4 * 8;

    float sd8[8];
    #pragma unroll
    for (int i = 0; i < 8; ++i) sd8[i] = sd[l4 * 8 + i];

    int accA[8] = {0, 0, 0, 0, 0, 0, 0, 0};
    int accB[8] = {0, 0, 0, 0, 0, 0, 0, 0};

    int j = r0 + q;
    for (; j + 12 < r1; j += 16) {   // 16 edges per wave-iter (4 per quarter)
        int s0 = csr[j], s1 = csr[j + 4], s2 = csr[j + 8], s3 = csr[j + 12];
        uint2 w0 = *(const uint2*)(xrow + (size_t)s0 * CH);
        uint2 w1 = *(const uint2*)(xrow + (size_t)s1 * CH);
        uint2 w2 = *(const uint2*)(xrow + (size_t)s2 * CH);
        uint2 w3 = *(const uint2*)(xrow + (size_t)s3 * CH);
        ACCI(accA, w0); ACCI(accA, w1);
        ACCI(accB, w2); ACCI(accB, w3);
    }
    for (; j < r1; j += 4) {
        uint2 w0 = *(const uint2*)(xrow + (size_t)csr[j] * CH);
        ACCI(accA, w0);
    }

    const float scdeg = d > 0 ? 1.0f / (float)d : 0.0f;
    float af[8];
    #pragma unroll
    for (int i = 0; i < 8; ++i) {
        int s = accA[i] + accB[i];
        s += __shfl_xor(s, 16);
        s += __shfl_xor(s, 32);
        af[i] = (float)s * sd8[i] * scdeg;
    }

    if (q == 0) {
        u16x8 ov;
        #pragma unroll
        for (int i = 0; i < 8; ++i) {
            float v = af[i];
            if (FOLD) v = d > 0 ? fmaf(v, ab[l4 * 8 + i], ab[128 + l4 * 8 + i]) : 0.f;
            ov[i] = f2bf(v);
        }
        *(u16x8*)&aggr[(size_t)node * CH + l4 * 8] = ov;
    }
}

// ---------------- MFMA GEMM: out = relu([A0|A1|A2] @ Wpack.T + bias) --------
// Round-9 proven. A concat along K (NT tiles of 64). Wpack: [128][NT*64] bf16.
// 128x128 block, 4 waves at 64x64, XOR-swizzled LDS via pre-swizzled source.

#define STAGE(buf, t) do {                                                           \
    const ushort_t* Ab_ = (((t) >> 1) == 0) ? A0 : ((((t) >> 1) == 1) ? A1 : A2);    \
    Ab_ += ((t) & 1) * 64;                                                           \
    const ushort_t* Wb_ = W + (t) * 64;                                              \
    _Pragma("unroll")                                                                \
    for (int i_ = 0; i_ < 4; ++i_) {                                                 \
        int f_ = i_ * 256 + tid;                                                     \
        int row_ = f_ >> 3;                                                          \
        int c_ = (f_ & 7) ^ (row_ & 7);                                              \
        int gr_ = bn0 + row_; gr_ = gr_ < NN ? gr_ : NN - 1;                         \
        __builtin_amdgcn_global_load_lds(                                            \
            (const AS1 unsigned int*)(Ab_ + (size_t)gr_ * CH + c_ * 8),              \
            (AS3 unsigned int*)(&Abuf[buf][f_ * 8]), 16, 0, 0);                      \
        __builtin_amdgcn_global_load_lds(                                            \
            (const AS1 unsigned int*)(Wb_ + (size_t)row_ * (NT * 64) + c_ * 8),      \
            (AS3 unsigned int*)(&Wbuf[buf][f_ * 8]), 16, 0, 0);                      \
    } } while (0)

template<int NT, bool STATS, bool F32OUT>
__global__ __launch_bounds__(256, 2) void k_mgemm(
    const ushort_t* __restrict__ A0, const ushort_t* __restrict__ A1,
    const ushort_t* __restrict__ A2,
    const ushort_t* __restrict__ W, const float* __restrict__ bias,
    ushort_t* __restrict__ outb, float* __restrict__ outf,
    float* __restrict__ bn_sums)
{
    __shared__ __align__(16) ushort_t Abuf[2][128 * 64];
    __shared__ __align__(16) ushort_t Wbuf[2][128 * 64];
    __shared__ float bns[128], bnq[128];

    const int tid  = threadIdx.x;
    const int lane = tid & 63;
    const int wid  = tid >> 6;
    const int l15  = lane & 15;
    const int lg   = lane >> 4;
    const int wn   = (wid >> 1) * 64;
    const int wo   = (wid & 1) * 64;
    const int bn0  = blockIdx.x * 128;

    if (STATS && tid < 128) { bns[tid] = 0.f; bnq[tid] = 0.f; }

    f32x4 acc[4][4];
    #pragma unroll
    for (int i = 0; i < 4; ++i)
        #pragma unroll
        for (int j = 0; j < 4; ++j)
            acc[i][j] = (f32x4){0.f, 0.f, 0.f, 0.f};

    STAGE(0, 0);
    asm volatile("s_waitcnt vmcnt(0)");
    __syncthreads();

    #pragma unroll
    for (int t = 0; t < NT; ++t) {
        const int cur = t & 1;
        if (t + 1 < NT) STAGE(cur ^ 1, t + 1);
        #pragma unroll
        for (int s = 0; s < 2; ++s) {
            short8_t af[4], wf[4];
            #pragma unroll
            for (int b = 0; b < 4; ++b) {
                int ra = wn + b * 16 + l15;
                int ca = (s * 4 + lg) ^ (ra & 7);
                af[b] = *(const short8_t*)&Abuf[cur][ra * 64 + ca * 8];
                int rw = wo + b * 16 + l15;
                int cw = (s * 4 + lg) ^ (rw & 7);
                wf[b] = *(const short8_t*)&Wbuf[cur][rw * 64 + cw * 8];
            }
            #pragma unroll
            for (int i = 0; i < 4; ++i)
                #pragma unroll
                for (int j = 0; j < 4; ++j)
                    acc[i][j] = __builtin_amdgcn_mfma_f32_16x16x32_bf16(
                        af[i], wf[j], acc[i][j], 0, 0, 0);
        }
        asm volatile("s_waitcnt vmcnt(0)");
        __syncthreads();
    }

    float bv[4];
    #pragma unroll
    for (int j = 0; j < 4; ++j) bv[j] = bias[wo + j * 16 + l15];

    float sum[4] = {0.f, 0.f, 0.f, 0.f}, sq[4] = {0.f, 0.f, 0.f, 0.f};

    #pragma unroll
    for (int i = 0; i < 4; ++i) {
        #pragma unroll
        for (int r = 0; r < 4; ++r) {
            int gn = bn0 + wn + i * 16 + lg * 4 + r;
            bool ok = gn < NN;
            #pragma unroll
            for (int j = 0; j < 4; ++j) {
                int o = wo + j * 16 + l15;
                float v = acc[i][j][r] + bv[j];
                v = fmaxf(v, 0.f);
                if (ok) {
                    if (F32OUT) outf[(size_t)gn * CH + o] = v;
                    else        outb[(size_t)gn * CH + o] = f2bf(v);
                    if (STATS) { sum[j] += v; sq[j] += v * v; }
                }
            }
        }
    }

    if (STATS) {
        #pragma unroll
        for (int j = 0; j < 4; ++j) {
            float ss = sum[j], qq = sq[j];
            ss += __shfl_xor(ss, 16); qq += __shfl_xor(qq, 16);
            ss += __shfl_xor(ss, 32); qq += __shfl_xor(qq, 32);
            if (lg == 0) {
                atomicAdd(&bns[wo + j * 16 + l15], ss);
                atomicAdd(&bnq[wo + j * 16 + l15], qq);
            }
        }
        __syncthreads();
        if (tid < 128) {
            atomicAdd(&bn_sums[tid], bns[tid]);
            atomicAdd(&bn_sums[128 + tid], bnq[tid]);
        }
    }
}

// ---------------- driver ----------------

extern "C" void kernel_launch(void* const* d_in, const int* in_sizes, int n_in,
                              void* d_out, int out_size, void* d_ws, size_t ws_size,
                              hipStream_t stream) {
    const float* x  = (const float*)d_in[0];
    const int*   ei = (const int*)d_in[1];
    const int* esrc = ei;
    const int* edst = ei + NE;

    const float* Wl[3] = {(const float*)d_in[2],  (const float*)d_in[7],  (const float*)d_in[12]};
    const float* bl[3] = {(const float*)d_in[3],  (const float*)d_in[8],  (const float*)d_in[13]};
    const float* Wr[3] = {(const float*)d_in[4],  (const float*)d_in[9],  (const float*)d_in[14]};
    const float* gg[3] = {(const float*)d_in[5],  (const float*)d_in[10], (const float*)d_in[15]};
    const float* bb[3] = {(const float*)d_in[6],  (const float*)d_in[11], (const float*)d_in[16]};
    const float* Wlin  = (const float*)d_in[17];
    const float* blin  = (const float*)d_in[18];

    float* fo = (float*)d_out;

    const size_t NC = (size_t)NN * CH;
    ushort_t* xb       = (ushort_t*)d_ws;
    ushort_t* y1b      = xb + NC;
    ushort_t* y2b      = y1b + NC;
    ushort_t* aggr_b   = y2b + NC;
    signed char* xq    = (signed char*)(aggr_b + NC);  // NC bytes, dead after aggr1
    signed char* y1q   = xq + NC;                      // NC bytes, dead after aggr2
    ushort_t* y3b      = (ushort_t*)xq;                // aliases xq+y1q (2*NC bytes)
    signed char* y2q   = y1q + NC;                     // NC bytes
    ushort_t* Wp1      = (ushort_t*)(y2q + NC);        // [128][256]
    ushort_t* Wp2      = Wp1 + 128 * 256;
    ushort_t* Wp3      = Wp2 + 128 * 256;
    ushort_t* WpF      = Wp3 + 128 * 256;              // [128][384]
    float* bias2       = (float*)(WpF + 128 * 384);
    float* bias3       = bias2 + 128;
    float* biasF       = bias3 + 128;
    float* bn_sums     = biasF + 128;                  // 3 x 256
    float* ab          = bn_sums + 768;                // 2 x 256 {a,c}
    float* sdx         = ab + 512;                     // 128 decode scales (x)
    float* sd1         = sdx + 128;
    float* sd2         = sd1 + 128;
    int* btot          = (int*)(sd2 + 128);            // 64
    int* boffs         = btot + 64;                    // 64
    int* deg           = boffs + 64;                   // NN
    int* cur           = deg + NN;                     // NN
    int* rp            = cur + NN;                     // NN+1
    int* csr           = rp + NN + 1;                  // NE

    // ---- CSR build ----
    hipMemsetAsync(deg, 0, 2 * NN * sizeof(int), stream);   // deg + cur
    k_hist<<<(NE + 255) / 256, 256, 0, stream>>>(edst, deg);
    k_scanA<<<NBLK, 1024, 0, stream>>>(deg, rp, btot);
    k_scanB<<<1, 64, 0, stream>>>(btot, boffs, rp);
    k_scanC<<<(NN + 255) / 256, 256, 0, stream>>>(rp, boffs);
    for (int p = 0; p < NPASS; ++p)
        k_fillp<<<NE / 256, 256, 0, stream>>>(esrc, edst, rp, cur, csr,
                                              p * PRANGE, (p + 1) * PRANGE);

    // ---- convert (bf16 + int8 fixed-scale) + layer-1 pack + bn_sums zero ----
    k_cvtpack<<<6250 + 128 + 1, 256, 0, stream>>>(x, xb, xq,
                                                  Wl[0], Wr[0], Wp1, bn_sums, sdx);

    const int GEMM_GRID = (NN + 127) / 128;        // 391
    const int AGGR_GRID = NN / 4;                  // 12500 (wave per node)
    const int FOLD_GRID = 128 + (NN * 16 + 255) / 256;

    // ---- layer 1 ----
    k_aggr8<false><<<AGGR_GRID, 256, 0, stream>>>(xq, rp, csr, sdx, nullptr, aggr_b);
    k_mgemm<4, true, false><<<GEMM_GRID, 256, 0, stream>>>(
        aggr_b, xb, nullptr, Wp1, bl[0], y1b, nullptr, bn_sums);
    k_foldreq<<<FOLD_GRID, 256, 0, stream>>>(bn_sums, gg[0], bb[0],
        Wl[1], Wr[1], bl[1], Wp2, bias2, ab, sd1, y1b, y1q);

    // ---- layer 2 ----
    k_aggr8<true><<<AGGR_GRID, 256, 0, stream>>>(y1q, rp, csr, sd1, ab, aggr_b);
    k_mgemm<4, true, false><<<GEMM_GRID, 256, 0, stream>>>(
        aggr_b, y1b, nullptr, Wp2, bias2, y2b, nullptr, bn_sums + 256);
    k_foldreq<<<FOLD_GRID, 256, 0, stream>>>(bn_sums + 256, gg[1], bb[1],
        Wl[2], Wr[2], bl[2], Wp3, bias3, ab + 256, sd2, y2b, y2q);

    // ---- layer 3 (y3b aliases dead xq+y1q region) ----
    k_aggr8<true><<<AGGR_GRID, 256, 0, stream>>>(y2q, rp, csr, sd2, ab + 256, aggr_b);
    k_mgemm<4, true, false><<<GEMM_GRID, 256, 0, stream>>>(
        aggr_b, y2b, nullptr, Wp3, bias3, y3b, nullptr, bn_sums + 512);
    k_foldF<<<128, 128, 0, stream>>>(bn_sums + 512, gg[2], bb[2], ab, ab + 256,
                                     Wlin, blin, WpF, biasF);

    // ---- final: relu([y1|y2|y3] @ WpF.T + biasF) -> fp32 d_out ----
    k_mgemm<6, false, true><<<GEMM_GRID, 256, 0, stream>>>(
        y1b, y2b, y3b, WpF, biasF, nullptr, fo, nullptr);
}

// Round 18
// 318.644 us; speedup vs baseline: 1.1103x; 1.0167x over previous
//
#include <hip/hip_runtime.h>

#define NN 50000
#define NE 800000
#define CH 128
#define EPSV 1e-5f
#define NPASS 2
#define PRANGE 25000
#define NBLK 49        // ceil(NN/1024) scan blocks

typedef unsigned short ushort_t;
typedef __attribute__((ext_vector_type(8))) short short8_t;
typedef __attribute__((ext_vector_type(8))) unsigned short u16x8;
typedef __attribute__((ext_vector_type(4))) float f32x4;

#define AS1 __attribute__((address_space(1)))
#define AS3 __attribute__((address_space(3)))

__device__ inline float bf2f(ushort_t u) {
    union { unsigned int i; float f; } t; t.i = ((unsigned int)u) << 16; return t.f;
}
__device__ inline ushort_t f2bf(float f) {
    union { float f; unsigned int i; } t; t.f = f;
    unsigned int r = t.i + 0x7fff + ((t.i >> 16) & 1);   // round-to-nearest-even
    return (ushort_t)(r >> 16);
}

// ---------------- CSR build ----------------

__global__ void k_hist(const int* __restrict__ dst, int* __restrict__ deg) {
    int e = blockIdx.x * 256 + threadIdx.x;
    if (e < NE) atomicAdd(&deg[dst[e]], 1);
}

// hierarchical scan, stage A: block-local exclusive scan -> rp (block-relative)
__global__ __launch_bounds__(1024) void k_scanA(const int* __restrict__ deg,
                                                int* __restrict__ rp,
                                                int* __restrict__ btot) {
    __shared__ int wsum[16];
    const int t = threadIdx.x;
    const int lane = t & 63;
    const int wid = t >> 6;
    const int i = blockIdx.x * 1024 + t;
    int v = (i < NN) ? deg[i] : 0;
    int x = v;
    #pragma unroll
    for (int off = 1; off < 64; off <<= 1) {
        int y = __shfl_up(x, off, 64);
        if (lane >= off) x += y;
    }
    if (lane == 63) wsum[wid] = x;
    __syncthreads();
    if (wid == 0 && lane < 16) {
        int s = wsum[lane];
        #pragma unroll
        for (int off = 1; off < 16; off <<= 1) {
            int y = __shfl_up(s, off, 16);
            if (lane >= off) s += y;
        }
        wsum[lane] = s;
    }
    __syncthreads();
    int wbase = (wid > 0) ? wsum[wid - 1] : 0;
    if (i < NN) rp[i] = wbase + x - v;
    if (wid == 15 && lane == 63) btot[blockIdx.x] = wbase + x;
}

// stage B: scan of block totals; writes grand total to rp[NN]
__global__ void k_scanB(const int* __restrict__ btot, int* __restrict__ boffs,
                        int* __restrict__ rp) {
    int t = threadIdx.x;                  // 64 threads
    int v = (t < NBLK) ? btot[t] : 0;
    int x = v;
    #pragma unroll
    for (int off = 1; off < 64; off <<= 1) {
        int y = __shfl_up(x, off, 64);
        if (t >= off) x += y;
    }
    if (t < NBLK) boffs[t] = x - v;
    if (t == NBLK - 1) rp[NN] = x;        // = NE
}

__global__ __launch_bounds__(256) void k_scanC(int* __restrict__ rp,
                                               const int* __restrict__ boffs) {
    int i = blockIdx.x * 256 + threadIdx.x;
    if (i < NN) rp[i] += boffs[i >> 10];
}

__global__ void k_fillp(const int* __restrict__ src, const int* __restrict__ dst,
                        const int* __restrict__ rp, int* __restrict__ cur,
                        int* __restrict__ csr, int lo, int hi) {
    int e = blockIdx.x * 256 + threadIdx.x;
    if (e < NE) {
        int d = dst[e];
        int s = src[e];
        if (d >= lo && d < hi) {
            int pos = rp[d] + atomicAdd(&cur[d], 1);
            csr[pos] = s;
        }
    }
}

// ---------------- fused input convert + layer-1 weight pack ----------------
// blocks [0, 6250): x fp32 -> bf16 (block 0 also zeroes bn_sums)
// blocks [6250, 6378): pack [Wl1 | Wr1] -> Wp1[o][256] bf16

__global__ __launch_bounds__(256) void k_cvtpack(const float* __restrict__ x,
        ushort_t* __restrict__ xb, const float* __restrict__ s0,
        const float* __restrict__ s1, ushort_t* __restrict__ Wp1,
        float* __restrict__ bn_sums) {
    if (blockIdx.x < 6250) {
        int i = blockIdx.x * 256 + threadIdx.x;      // float4 index
        if (blockIdx.x == 0) {
            bn_sums[threadIdx.x] = 0.f;
            bn_sums[256 + threadIdx.x] = 0.f;
            bn_sums[512 + threadIdx.x] = 0.f;
        }
        if (i >= NN * 32) return;
        float4 v = ((const float4*)x)[i];
        ushort4 o;
        o.x = f2bf(v.x); o.y = f2bf(v.y); o.z = f2bf(v.z); o.w = f2bf(v.w);
        ((ushort4*)xb)[i] = o;
    } else {
        int t = (blockIdx.x - 6250) * 256 + threadIdx.x;   // 128*256
        int o = t >> 8, k = t & 255;
        float v = (k < 128) ? s0[o * 128 + k] : s1[o * 128 + k - 128];
        Wp1[t] = f2bf(v);
    }
}

// fused BN-finalize + next-layer fold:
//   a = g*rsqrt(var+eps), c = b - a*mu  (from bn_sums of layer l)
//   Wp_{l+1} = [Wl | Wr*a], bias_{l+1} = bl + Wr@c; block 0 stores {a,c} -> abg
__global__ void k_foldnext(const float* __restrict__ bn_sums,
                           const float* __restrict__ g, const float* __restrict__ b,
                           const float* __restrict__ Wl, const float* __restrict__ Wr,
                           const float* __restrict__ bl,
                           ushort_t* __restrict__ Wp, float* __restrict__ bias,
                           float* __restrict__ abg) {
    __shared__ float red[128];
    int o = blockIdx.x;
    int k = threadIdx.x;
    float mu = bn_sums[k] * (1.0f / NN);
    float var = bn_sums[128 + k] * (1.0f / NN) - mu * mu;
    var = var > 0.f ? var : 0.f;
    float a = g[k] * rsqrtf(var + EPSV);
    float c = b[k] - a * mu;
    if (o == 0) { abg[k] = a; abg[128 + k] = c; }
    float wr = Wr[o * 128 + k];
    Wp[o * 256 + k]       = f2bf(Wl[o * 128 + k]);
    Wp[o * 256 + 128 + k] = f2bf(wr * a);
    red[k] = wr * c;
    __syncthreads();
    for (int s = 64; s > 0; s >>= 1) {
        if (k < s) red[k] += red[k + s];
        __syncthreads();
    }
    if (k == 0) bias[o] = bl[o] + red[0];
}

// final fold: layer-3 BN finalize + Wlin fold (uses stored ab1, ab2)
__global__ void k_foldF(const float* __restrict__ bn3,
                        const float* __restrict__ g3, const float* __restrict__ b3,
                        const float* __restrict__ ab1, const float* __restrict__ ab2,
                        const float* __restrict__ Wlin, const float* __restrict__ blin,
                        ushort_t* __restrict__ Wp, float* __restrict__ bias) {
    __shared__ float red[128];
    int o = blockIdx.x;
    int k = threadIdx.x;
    float mu = bn3[k] * (1.0f / NN);
    float var = bn3[128 + k] * (1.0f / NN) - mu * mu;
    var = var > 0.f ? var : 0.f;
    float a3 = g3[k] * rsqrtf(var + EPSV);
    float c3 = b3[k] - a3 * mu;
    float w1 = Wlin[o * 384 + k];
    float w2 = Wlin[o * 384 + 128 + k];
    float w3 = Wlin[o * 384 + 256 + k];
    Wp[o * 384 + k]       = f2bf(w1 * ab1[k]);
    Wp[o * 384 + 128 + k] = f2bf(w2 * ab2[k]);
    Wp[o * 384 + 256 + k] = f2bf(w3 * a3);
    red[k] = w1 * ab1[128 + k] + w2 * ab2[128 + k] + w3 * c3;
    __syncthreads();
    for (int s = 64; s > 0; s >>= 1) {
        if (k < s) red[k] += red[k + s];
        __syncthreads();
    }
    if (k == 0) bias[o] = blin[o] + red[0];
}

// ---------------- mean aggregation (round-5/9 proven: 49.5us) ---------------
// One wave per node; 16 lanes cover the 256B row; 4 quarters x 4 streams =
// 16 edges per wave-iter (4 independent row-loads in flight per lane) — the
// measured concurrency floor at mean degree 16 (invariant across 7 variants).
// FOLD: output = deg>0 ? a * mean(y) + c : 0 (prev layer's BN folded in).

template<bool FOLD>
__global__ __launch_bounds__(256) void k_aggr(const ushort_t* __restrict__ x,
        const int* __restrict__ rp, const int* __restrict__ csr,
        const float* __restrict__ ab, ushort_t* __restrict__ aggr) {
    const int node = blockIdx.x * 4 + (threadIdx.x >> 6);   // grid = NN/4 exact
    const int lane = threadIdx.x & 63;
    const int l4 = lane & 15;        // channel group: ch l4*8 .. l4*8+7
    const int q  = lane >> 4;        // edge phase 0..3
    const int r0 = rp[node], r1 = rp[node + 1];
    const int d = r1 - r0;
    const ushort_t* xrow = x + l4 * 8;

    float accA[8] = {0, 0, 0, 0, 0, 0, 0, 0};
    float accB[8] = {0, 0, 0, 0, 0, 0, 0, 0};

    int j = r0 + q;
    for (; j + 12 < r1; j += 16) {   // 16 edges per wave-iter (4 per quarter)
        int s0 = csr[j], s1 = csr[j + 4], s2 = csr[j + 8], s3 = csr[j + 12];
        u16x8 v0 = *(const u16x8*)(xrow + (size_t)s0 * CH);
        u16x8 v1 = *(const u16x8*)(xrow + (size_t)s1 * CH);
        u16x8 v2 = *(const u16x8*)(xrow + (size_t)s2 * CH);
        u16x8 v3 = *(const u16x8*)(xrow + (size_t)s3 * CH);
        #pragma unroll
        for (int i = 0; i < 8; ++i) {
            accA[i] += bf2f(v0[i]) + bf2f(v1[i]);
            accB[i] += bf2f(v2[i]) + bf2f(v3[i]);
        }
    }
    for (; j < r1; j += 4) {
        int s0 = csr[j];
        u16x8 v0 = *(const u16x8*)(xrow + (size_t)s0 * CH);
        #pragma unroll
        for (int i = 0; i < 8; ++i) accA[i] += bf2f(v0[i]);
    }

    const float sc = d > 0 ? 1.0f / (float)d : 0.0f;
    #pragma unroll
    for (int i = 0; i < 8; ++i) {
        float s = accA[i] + accB[i];
        s += __shfl_xor(s, 16);
        s += __shfl_xor(s, 32);
        accA[i] = s * sc;
    }

    if (q == 0) {
        u16x8 ov;
        #pragma unroll
        for (int i = 0; i < 8; ++i) {
            float v = accA[i];
            if (FOLD) v = d > 0 ? fmaf(v, ab[l4 * 8 + i], ab[128 + l4 * 8 + i]) : 0.f;
            ov[i] = f2bf(v);
        }
        *(u16x8*)&aggr[(size_t)node * CH + l4 * 8] = ov;
    }
}

// ---------------- MFMA GEMM: out = relu([A0|A1|A2] @ Wpack.T + bias) --------
// A logically concatenated along K (NT tiles of 64). Wpack: [128][NT*64] bf16.
// Block: 128 nodes x 128 outs, 4 waves at 64x64. LDS XOR-swizzled (T2) via
// pre-swizzled global source (rule 21): linear dest + c^(row&7) src + swz read.

#define STAGE(buf, t) do {                                                           \
    const ushort_t* Ab_ = (((t) >> 1) == 0) ? A0 : ((((t) >> 1) == 1) ? A1 : A2);    \
    Ab_ += ((t) & 1) * 64;                                                           \
    const ushort_t* Wb_ = W + (t) * 64;                                              \
    _Pragma("unroll")                                                                \
    for (int i_ = 0; i_ < 4; ++i_) {                                                 \
        int f_ = i_ * 256 + tid;                                                     \
        int row_ = f_ >> 3;                                                          \
        int c_ = (f_ & 7) ^ (row_ & 7);                                              \
        int gr_ = bn0 + row_; gr_ = gr_ < NN ? gr_ : NN - 1;                         \
        __builtin_amdgcn_global_load_lds(                                            \
            (const AS1 unsigned int*)(Ab_ + (size_t)gr_ * CH + c_ * 8),              \
            (AS3 unsigned int*)(&Abuf[buf][f_ * 8]), 16, 0, 0);                      \
        __builtin_amdgcn_global_load_lds(                                            \
            (const AS1 unsigned int*)(Wb_ + (size_t)row_ * (NT * 64) + c_ * 8),      \
            (AS3 unsigned int*)(&Wbuf[buf][f_ * 8]), 16, 0, 0);                      \
    } } while (0)

template<int NT, bool STATS, bool F32OUT>
__global__ __launch_bounds__(256, 2) void k_mgemm(
    const ushort_t* __restrict__ A0, const ushort_t* __restrict__ A1,
    const ushort_t* __restrict__ A2,
    const ushort_t* __restrict__ W, const float* __restrict__ bias,
    ushort_t* __restrict__ outb, float* __restrict__ outf,
    float* __restrict__ bn_sums)
{
    __shared__ __align__(16) ushort_t Abuf[2][128 * 64];
    __shared__ __align__(16) ushort_t Wbuf[2][128 * 64];
    __shared__ float bns[128], bnq[128];

    const int tid  = threadIdx.x;
    const int lane = tid & 63;
    const int wid  = tid >> 6;
    const int l15  = lane & 15;
    const int lg   = lane >> 4;
    const int wn   = (wid >> 1) * 64;   // wave node-origin within tile
    const int wo   = (wid & 1) * 64;    // wave out-origin within tile
    const int bn0  = blockIdx.x * 128;

    if (STATS && tid < 128) { bns[tid] = 0.f; bnq[tid] = 0.f; }

    f32x4 acc[4][4];
    #pragma unroll
    for (int i = 0; i < 4; ++i)
        #pragma unroll
        for (int j = 0; j < 4; ++j)
            acc[i][j] = (f32x4){0.f, 0.f, 0.f, 0.f};

    STAGE(0, 0);
    asm volatile("s_waitcnt vmcnt(0)");
    __syncthreads();

    #pragma unroll
    for (int t = 0; t < NT; ++t) {
        const int cur = t & 1;
        if (t + 1 < NT) STAGE(cur ^ 1, t + 1);
        #pragma unroll
        for (int s = 0; s < 2; ++s) {
            short8_t af[4], wf[4];
            #pragma unroll
            for (int b = 0; b < 4; ++b) {
                int ra = wn + b * 16 + l15;
                int ca = (s * 4 + lg) ^ (ra & 7);
                af[b] = *(const short8_t*)&Abuf[cur][ra * 64 + ca * 8];
                int rw = wo + b * 16 + l15;
                int cw = (s * 4 + lg) ^ (rw & 7);
                wf[b] = *(const short8_t*)&Wbuf[cur][rw * 64 + cw * 8];
            }
            #pragma unroll
            for (int i = 0; i < 4; ++i)
                #pragma unroll
                for (int j = 0; j < 4; ++j)
                    acc[i][j] = __builtin_amdgcn_mfma_f32_16x16x32_bf16(
                        af[i], wf[j], acc[i][j], 0, 0, 0);
        }
        asm volatile("s_waitcnt vmcnt(0)");
        __syncthreads();
    }

    // epilogue: bias + relu + store (+ BN stats from fp32 acc)
    float bv[4];
    #pragma unroll
    for (int j = 0; j < 4; ++j) bv[j] = bias[wo + j * 16 + l15];

    float sum[4] = {0.f, 0.f, 0.f, 0.f}, sq[4] = {0.f, 0.f, 0.f, 0.f};

    #pragma unroll
    for (int i = 0; i < 4; ++i) {
        #pragma unroll
        for (int r = 0; r < 4; ++r) {
            int gn = bn0 + wn + i * 16 + lg * 4 + r;
            bool ok = gn < NN;
            #pragma unroll
            for (int j = 0; j < 4; ++j) {
                int o = wo + j * 16 + l15;
                float v = acc[i][j][r] + bv[j];
                v = fmaxf(v, 0.f);
                if (ok) {
                    if (F32OUT) outf[(size_t)gn * CH + o] = v;
                    else        outb[(size_t)gn * CH + o] = f2bf(v);
                    if (STATS) { sum[j] += v; sq[j] += v * v; }
                }
            }
        }
    }

    if (STATS) {
        #pragma unroll
        for (int j = 0; j < 4; ++j) {
            float ss = sum[j], qq = sq[j];
            ss += __shfl_xor(ss, 16); qq += __shfl_xor(qq, 16);
            ss += __shfl_xor(ss, 32); qq += __shfl_xor(qq, 32);
            if (lg == 0) {
                atomicAdd(&bns[wo + j * 16 + l15], ss);
                atomicAdd(&bnq[wo + j * 16 + l15], qq);
            }
        }
        __syncthreads();
        if (tid < 128) {
            atomicAdd(&bn_sums[tid], bns[tid]);
            atomicAdd(&bn_sums[128 + tid], bnq[tid]);
        }
    }
}

// ---------------- driver ----------------

extern "C" void kernel_launch(void* const* d_in, const int* in_sizes, int n_in,
                              void* d_out, int out_size, void* d_ws, size_t ws_size,
                              hipStream_t stream) {
    const float* x  = (const float*)d_in[0];
    const int*   ei = (const int*)d_in[1];
    const int* esrc = ei;
    const int* edst = ei + NE;

    const float* Wl[3] = {(const float*)d_in[2],  (const float*)d_in[7],  (const float*)d_in[12]};
    const float* bl[3] = {(const float*)d_in[3],  (const float*)d_in[8],  (const float*)d_in[13]};
    const float* Wr[3] = {(const float*)d_in[4],  (const float*)d_in[9],  (const float*)d_in[14]};
    const float* gg[3] = {(const float*)d_in[5],  (const float*)d_in[10], (const float*)d_in[15]};
    const float* bb[3] = {(const float*)d_in[6],  (const float*)d_in[11], (const float*)d_in[16]};
    const float* Wlin  = (const float*)d_in[17];
    const float* blin  = (const float*)d_in[18];

    float* fo = (float*)d_out;

    const size_t NC = (size_t)NN * CH;
    ushort_t* xb     = (ushort_t*)d_ws;
    ushort_t* y1b    = xb + NC;
    ushort_t* y2b    = y1b + NC;
    ushort_t* y3b    = y2b + NC;
    ushort_t* aggr_b = y3b + NC;
    ushort_t* Wp1    = aggr_b + NC;            // [128][256]
    ushort_t* Wp2    = Wp1 + 128 * 256;
    ushort_t* Wp3    = Wp2 + 128 * 256;
    ushort_t* WpF    = Wp3 + 128 * 256;        // [128][384]
    float* bias2     = (float*)(WpF + 128 * 384);
    float* bias3     = bias2 + 128;
    float* biasF     = bias3 + 128;
    float* bn_sums   = biasF + 128;            // 3 x 256
    float* ab        = bn_sums + 768;          // 2 x 256 (layer-1, layer-2 {a,c})
    int* btot        = (int*)(ab + 512);       // 64
    int* boffs       = btot + 64;              // 64
    int* deg         = boffs + 64;             // NN
    int* cur         = deg + NN;               // NN fill cursors
    int* rp          = cur + NN;               // NN+1
    int* csr         = rp + NN + 1;            // NE

    // ---- CSR build (hierarchical scan, bucketed 2-pass fill) ----
    hipMemsetAsync(deg, 0, 2 * NN * sizeof(int), stream);   // deg + cur
    k_hist<<<(NE + 255) / 256, 256, 0, stream>>>(edst, deg);
    k_scanA<<<NBLK, 1024, 0, stream>>>(deg, rp, btot);
    k_scanB<<<1, 64, 0, stream>>>(btot, boffs, rp);
    k_scanC<<<(NN + 255) / 256, 256, 0, stream>>>(rp, boffs);
    for (int p = 0; p < NPASS; ++p)
        k_fillp<<<NE / 256, 256, 0, stream>>>(esrc, edst, rp, cur, csr,
                                              p * PRANGE, (p + 1) * PRANGE);

    // ---- input convert + layer-1 pack (one dispatch; also zeroes bn_sums) ----
    k_cvtpack<<<6250 + 128, 256, 0, stream>>>(x, xb, Wl[0], Wr[0], Wp1, bn_sums);

    const int GEMM_GRID = (NN + 127) / 128;    // 391
    const int AGGR_GRID = NN / 4;              // 12500 (wave per node)

    // ---- layer 1 ----
    k_aggr<false><<<AGGR_GRID, 256, 0, stream>>>(xb, rp, csr, nullptr, aggr_b);
    k_mgemm<4, true, false><<<GEMM_GRID, 256, 0, stream>>>(
        aggr_b, xb, nullptr, Wp1, bl[0], y1b, nullptr, bn_sums);
    k_foldnext<<<128, 128, 0, stream>>>(bn_sums, gg[0], bb[0],
                                        Wl[1], Wr[1], bl[1], Wp2, bias2, ab);

    // ---- layer 2 ----
    k_aggr<true><<<AGGR_GRID, 256, 0, stream>>>(y1b, rp, csr, ab, aggr_b);
    k_mgemm<4, true, false><<<GEMM_GRID, 256, 0, stream>>>(
        aggr_b, y1b, nullptr, Wp2, bias2, y2b, nullptr, bn_sums + 256);
    k_foldnext<<<128, 128, 0, stream>>>(bn_sums + 256, gg[1], bb[1],
                                        Wl[2], Wr[2], bl[2], Wp3, bias3, ab + 256);

    // ---- layer 3 ----
    k_aggr<true><<<AGGR_GRID, 256, 0, stream>>>(y2b, rp, csr, ab + 256, aggr_b);
    k_mgemm<4, true, false><<<GEMM_GRID, 256, 0, stream>>>(
        aggr_b, y2b, nullptr, Wp3, bias3, y3b, nullptr, bn_sums + 512);
    k_foldF<<<128, 128, 0, stream>>>(bn_sums + 512, gg[2], bb[2], ab, ab + 256,
                                     Wlin, blin, WpF, biasF);

    // ---- final: relu([y1|y2|y3] @ WpF.T + biasF) -> fp32 d_out ----
    k_mgemm<6, false, true><<<GEMM_GRID, 256, 0, stream>>>(
        y1b, y2b, y3b, WpF, biasF, nullptr, fo, nullptr);
}